// Round 2
// baseline (1073.038 us; speedup 1.0000x reference)
//
#include <hip/hip_runtime.h>
#include <math.h>

#define B_ 8
#define C_ 64
#define N_ 4096
#define K_ 20
#define O_ 64
#define CS 4          // column segments for knn kernel
#define TC 128        // columns per LDS tile
#define NKf 81920.0f  // N*K
#define EPS 1e-5f
#define SLOPE 0.2f

// 20-deep sorted insert (descending); tv/ti are unrolled register arrays.
#define INS20(sv, mv)                                            \
  {                                                              \
    _Pragma("unroll")                                            \
    for (int j = 19; j >= 1; --j) {                              \
      bool sh = (sv) > tv[j - 1];                                \
      bool he = (!sh) && ((sv) > tv[j]);                         \
      tv[j] = sh ? tv[j - 1] : (he ? (sv) : tv[j]);              \
      ti[j] = sh ? ti[j - 1] : (he ? (mv) : ti[j]);              \
    }                                                            \
    if ((sv) > tv[0]) { tv[0] = (sv); ti[0] = (mv); }            \
  }

// ---------------- Kernel A: xx = sum_c x^2, P = W1^T x, Q = (W2-W1)^T x ----------------
__global__ __launch_bounds__(256) void ka(const float* __restrict__ x,
                                          const float* __restrict__ W,
                                          float* __restrict__ xx,
                                          float* __restrict__ Pt,
                                          float* __restrict__ Qt) {
  __shared__ float wl[O_ * 128];
  int t = threadIdx.x;
#pragma unroll
  for (int j = 0; j < 32; ++j) wl[t + 256 * j] = W[t + 256 * j];
  __syncthreads();
  int gid = blockIdx.x * 256 + t;  // (b,n) flat, 0..32767
  int b = gid >> 12;
  int n = gid & 4095;
  const float* xb = x + (size_t)b * C_ * N_ + n;
  float xr[64];
  float sq = 0.f;
#pragma unroll
  for (int c = 0; c < 64; ++c) {
    xr[c] = xb[(size_t)c * N_];
    sq = fmaf(xr[c], xr[c], sq);
  }
  xx[gid] = sq;
  float* prow = Pt + (size_t)gid * 64;
  float* qrow = Qt + (size_t)gid * 64;
  for (int o = 0; o < 64; ++o) {
    const float4* w1 = (const float4*)&wl[o * 128];
    const float4* w2 = (const float4*)&wl[o * 128 + 64];
    float pa = 0.f, pb = 0.f, qa = 0.f, qb = 0.f;
#pragma unroll
    for (int c4 = 0; c4 < 16; c4 += 2) {
      float4 wa = w1[c4], wb = w1[c4 + 1];
      float4 va = w2[c4], vb = w2[c4 + 1];
      pa = fmaf(xr[4 * c4 + 0], wa.x, pa);
      pa = fmaf(xr[4 * c4 + 1], wa.y, pa);
      pa = fmaf(xr[4 * c4 + 2], wa.z, pa);
      pa = fmaf(xr[4 * c4 + 3], wa.w, pa);
      pb = fmaf(xr[4 * c4 + 4], wb.x, pb);
      pb = fmaf(xr[4 * c4 + 5], wb.y, pb);
      pb = fmaf(xr[4 * c4 + 6], wb.z, pb);
      pb = fmaf(xr[4 * c4 + 7], wb.w, pb);
      qa = fmaf(xr[4 * c4 + 0], va.x, qa);
      qa = fmaf(xr[4 * c4 + 1], va.y, qa);
      qa = fmaf(xr[4 * c4 + 2], va.z, qa);
      qa = fmaf(xr[4 * c4 + 3], va.w, qa);
      qb = fmaf(xr[4 * c4 + 4], vb.x, qb);
      qb = fmaf(xr[4 * c4 + 5], vb.y, qb);
      qb = fmaf(xr[4 * c4 + 6], vb.z, qb);
      qb = fmaf(xr[4 * c4 + 7], vb.w, qb);
    }
    float p = pa + pb;
    prow[o] = p;
    qrow[o] = (qa + qb) - p;
  }
}

// ---------------- Kernel B: fused distance + per-row top-20 (per column segment) ----------------
// rank by s = 2*dot(x_n, x_m) - xx[m]   (the -xx[n] term is row-constant)
__global__ __launch_bounds__(256) void kb(const float* __restrict__ x,
                                          const float* __restrict__ xx,
                                          float* __restrict__ candv,
                                          int* __restrict__ candi) {
  __shared__ float tile[TC * 68];  // [m][c], stride 68 (16B-aligned rows), xx at c=64
  int seg = blockIdx.x;  // 0..CS-1
  int rb = blockIdx.y;   // 0..15
  int b = blockIdx.z;    // 0..7
  int t = threadIdx.x;
  int n = rb * 256 + t;
  const float* xb = x + (size_t)b * C_ * N_;
  float xr2[64];
#pragma unroll
  for (int c = 0; c < 64; ++c) xr2[c] = 2.f * xb[(size_t)c * N_ + n];
  float tv[20];
  int ti[20];
#pragma unroll
  for (int j = 0; j < 20; ++j) { tv[j] = -INFINITY; ti[j] = 0; }
  // 4-slot per-lane pending FIFO (registers, static indexing only)
  float pv0 = 0.f, pv1 = 0.f, pv2 = 0.f, pv3 = 0.f;
  int pm0 = 0, pm1 = 0, pm2 = 0, pm3 = 0;
  int pcnt = 0;
  auto drain = [&]() {
    while (__any(pcnt > 0)) {
      bool a = pcnt > 0;
      float s2 = pv0;
      int m2 = pm0;
      if (a) {
        pv0 = pv1; pm0 = pm1;
        pv1 = pv2; pm1 = pm2;
        pv2 = pv3; pm2 = pm3;
        pcnt--;
        if (s2 > tv[19]) INS20(s2, m2);
      }
    }
  };
  const int m0s = seg * (N_ / CS);
  for (int tt = 0; tt < (N_ / CS) / TC; ++tt) {
    int m0 = m0s + tt * TC;
    __syncthreads();
#pragma unroll
    for (int j = 0; j < 8; ++j) {   // 2048 float4 = 128 m x 64 c
      int f4 = t + 256 * j;
      int c = f4 >> 5;              // 0..63
      int m4 = (f4 & 31) * 4;      // 0..124
      float4 v = *(const float4*)&xb[(size_t)c * N_ + m0 + m4];
      tile[(m4 + 0) * 68 + c] = v.x;
      tile[(m4 + 1) * 68 + c] = v.y;
      tile[(m4 + 2) * 68 + c] = v.z;
      tile[(m4 + 3) * 68 + c] = v.w;
    }
    if (t < TC) tile[t * 68 + 64] = xx[(size_t)b * N_ + m0 + t];
    __syncthreads();
    for (int mm = 0; mm < TC; ++mm) {
      const float4* col = (const float4*)&tile[mm * 68];
      float a0 = -tile[mm * 68 + 64], a1 = 0.f, a2 = 0.f, a3 = 0.f;
#pragma unroll
      for (int c4 = 0; c4 < 16; ++c4) {
        float4 v = col[c4];
        a0 = fmaf(xr2[4 * c4 + 0], v.x, a0);
        a1 = fmaf(xr2[4 * c4 + 1], v.y, a1);
        a2 = fmaf(xr2[4 * c4 + 2], v.z, a2);
        a3 = fmaf(xr2[4 * c4 + 3], v.w, a3);
      }
      float s = (a0 + a1) + (a2 + a3);
      int m = m0 + mm;
      bool q = s > tv[19];
      if (__any(q)) {
        if (q) {
          // push into FIFO slot pcnt (static cndmask chain)
          pv3 = (pcnt == 3) ? s : pv3; pm3 = (pcnt == 3) ? m : pm3;
          pv2 = (pcnt == 2) ? s : pv2; pm2 = (pcnt == 2) ? m : pm2;
          pv1 = (pcnt == 1) ? s : pv1; pm1 = (pcnt == 1) ? m : pm1;
          pv0 = (pcnt == 0) ? s : pv0; pm0 = (pcnt == 0) ? m : pm0;
          pcnt++;
        }
        if (__any(pcnt == 4)) drain();
      }
    }
  }
  drain();
  size_t base = ((size_t)(b * N_ + n) * CS + seg) * 20;
#pragma unroll
  for (int j = 0; j < 20; ++j) {
    candv[base + j] = tv[j];
    candi[base + j] = ti[j];
  }
}

// ---------------- Merge partial top-20 lists ----------------
__global__ __launch_bounds__(256) void kmerge(const float* __restrict__ candv,
                                              const int* __restrict__ candi,
                                              int* __restrict__ idxf) {
  int r = blockIdx.x * 256 + threadIdx.x;  // 0..32767
  const float* cv = candv + (size_t)r * (CS * 20);
  const int* ci = candi + (size_t)r * (CS * 20);
  float tv[20];
  int ti[20];
#pragma unroll
  for (int j = 0; j < 20; ++j) { tv[j] = -INFINITY; ti[j] = 0; }
  for (int seg = 0; seg < CS; ++seg) {
    const float* cvs = cv + seg * 20;
    const int* cis = ci + seg * 20;
    for (int j = 0; j < 20; ++j) {
      float s = cvs[j];
      if (!(s > tv[19])) break;  // seg list sorted desc: rest can't qualify
      int m = cis[j];
      INS20(s, m);
    }
  }
  int* op = idxf + (size_t)r * 20;
#pragma unroll
  for (int j = 0; j < 20; ++j) op[j] = ti[j];
}

// ---------------- Kernel D: gather P at neighbors, stats, M = max_k P + Q ----------------
__global__ __launch_bounds__(256) void kd(const float* __restrict__ Pt,
                                          const float* __restrict__ Qt,
                                          const int* __restrict__ idxf,
                                          float* __restrict__ Mt,
                                          float* __restrict__ S1,
                                          float* __restrict__ S2) {
  int bi = blockIdx.x;  // 0..2047
  int b = bi >> 8;
  int n0 = (bi & 255) * 16;
  int w = threadIdx.x >> 6;
  int o = threadIdx.x & 63;
  const float* Pb = Pt + (size_t)b * N_ * 64;
  float s1 = 0.f, s2 = 0.f;
#pragma unroll
  for (int r = 0; r < 4; ++r) {
    int n = n0 + w * 4 + r;
    const int* ip = idxf + (size_t)(b * N_ + n) * 20;
    float a = 0.f, bb = 0.f, mx = -INFINITY;
#pragma unroll
    for (int k = 0; k < 20; ++k) {
      int m = ip[k];
      float v = Pb[(size_t)m * 64 + o];
      a += v;
      bb = fmaf(v, v, bb);
      mx = fmaxf(mx, v);
    }
    float q = Qt[(size_t)(b * N_ + n) * 64 + o];
    Mt[(size_t)(b * N_ + n) * 64 + o] = mx + q;
    s1 += a + 20.f * q;
    s2 += bb + 2.f * q * a + 20.f * q * q;
  }
  __shared__ float red[8][64];
  red[w][o] = s1;
  red[4 + w][o] = s2;
  __syncthreads();
  if (threadIdx.x < 64) {
    float t1 = red[0][o] + red[1][o] + red[2][o] + red[3][o];
    float t2 = red[4][o] + red[5][o] + red[6][o] + red[7][o];
    atomicAdd(&S1[b * 64 + o], t1);
    atomicAdd(&S2[b * 64 + o], t2);
  }
}

// ---------------- Kernel E: normalize + leaky + transpose to (B,O,N) ----------------
__global__ __launch_bounds__(256) void ke(const float* __restrict__ Mt,
                                          const float* __restrict__ S1,
                                          const float* __restrict__ S2,
                                          float* __restrict__ out) {
  __shared__ float tile[64 * 65];
  __shared__ float mu[64], rs[64];
  int bi = blockIdx.x;  // 0..511
  int b = bi >> 6;
  int n0 = (bi & 63) * 64;
  int t = threadIdx.x;
  if (t < 64) {
    float m = S1[b * 64 + t] * (1.f / NKf);
    float v = S2[b * 64 + t] * (1.f / NKf) - m * m;
    mu[t] = m;
    rs[t] = rsqrtf(v + EPS);
  }
#pragma unroll
  for (int rr = 0; rr < 16; ++rr) {
    int f = t + rr * 256;
    int nl = f >> 6, o = f & 63;
    tile[nl * 65 + o] = Mt[((size_t)b * N_ + n0 + nl) * 64 + o];
  }
  __syncthreads();
#pragma unroll
  for (int rr = 0; rr < 16; ++rr) {
    int f = t + rr * 256;
    int o = f >> 6, nl = f & 63;
    float v = (tile[nl * 65 + o] - mu[o]) * rs[o];
    v = v > 0.f ? v : SLOPE * v;
    out[((size_t)b * 64 + o) * N_ + n0 + nl] = v;
  }
}

extern "C" void kernel_launch(void* const* d_in, const int* in_sizes, int n_in,
                              void* d_out, int out_size, void* d_ws, size_t ws_size,
                              hipStream_t stream) {
  const float* x = (const float*)d_in[0];
  const float* W = (const float*)d_in[1];
  float* out = (float*)d_out;
  float* ws = (float*)d_ws;
  float* xx = ws;                           // 32768
  float* Pt = xx + 32768;                   // 2097152  P[b][n][o]
  float* Qt = Pt + 2097152;                 // 2097152  Q[b][n][o]
  float* candv = Qt + 2097152;              // 2621440
  int* candi = (int*)(candv + 2621440);     // 2621440
  int* idxf = candi + 2621440;              // 655360
  float* S1 = (float*)(idxf + 655360);      // 512
  float* S2 = S1 + 512;                     // 512
  float* Mt = candv;  // alias: candv dead after kmerge; Mt (2097152) fits inside

  hipLaunchKernelGGL(ka, dim3(128), dim3(256), 0, stream, x, W, xx, Pt, Qt);
  hipLaunchKernelGGL(kb, dim3(CS, 16, 8), dim3(256), 0, stream, x, xx, candv, candi);
  hipLaunchKernelGGL(kmerge, dim3(128), dim3(256), 0, stream, candv, candi, idxf);
  hipMemsetAsync(S1, 0, 1024 * sizeof(float), stream);
  hipLaunchKernelGGL(kd, dim3(2048), dim3(256), 0, stream, Pt, Qt, idxf, Mt, S1, S2);
  hipLaunchKernelGGL(ke, dim3(512), dim3(256), 0, stream, Mt, S1, S2, out);
}

// Round 3
// 759.701 us; speedup vs baseline: 1.4124x; 1.4124x over previous
//
#include <hip/hip_runtime.h>
#include <math.h>

#define B_ 8
#define C_ 64
#define N_ 4096
#define K_ 20
#define O_ 64
#define CS 8          // column segments for knn kernel
#define NKf 81920.0f  // N*K
#define EPS 1e-5f
#define SLOPE 0.2f

// 20-deep sorted insert (descending); tv/ti are unrolled register arrays.
#define INS20(sv, mv)                                            \
  {                                                              \
    _Pragma("unroll")                                            \
    for (int j = 19; j >= 1; --j) {                              \
      bool sh = (sv) > tv[j - 1];                                \
      bool he = (!sh) && ((sv) > tv[j]);                         \
      tv[j] = sh ? tv[j - 1] : (he ? (sv) : tv[j]);              \
      ti[j] = sh ? ti[j - 1] : (he ? (mv) : ti[j]);              \
    }                                                            \
    if ((sv) > tv[0]) { tv[0] = (sv); ti[0] = (mv); }            \
  }

// ---- Kernel A: xx = sum_c x^2, xT[b][n][c] = x, P = W1^T x, Q = (W2-W1)^T x ----
__global__ __launch_bounds__(256, 3) void ka(const float* __restrict__ x,
                                             const float* __restrict__ W,
                                             float* __restrict__ xx,
                                             float* __restrict__ xT,
                                             float* __restrict__ Pt,
                                             float* __restrict__ Qt) {
  __shared__ float wl[O_ * 128];
  int t = threadIdx.x;
#pragma unroll
  for (int j = 0; j < 32; ++j) wl[t + 256 * j] = W[t + 256 * j];
  __syncthreads();
  int gid = blockIdx.x * 256 + t;  // (b,n) flat, 0..32767
  int b = gid >> 12;
  int n = gid & 4095;
  const float* xb = x + (size_t)b * C_ * N_ + n;
  float xr[64];
  float sq = 0.f;
#pragma unroll
  for (int c = 0; c < 64; ++c) {
    xr[c] = xb[(size_t)c * N_];
    sq = fmaf(xr[c], xr[c], sq);
  }
  xx[gid] = sq;
  float* xtrow = xT + (size_t)gid * 64;
#pragma unroll
  for (int c4 = 0; c4 < 16; ++c4) {
    *(float4*)&xtrow[c4 * 4] =
        make_float4(xr[4 * c4], xr[4 * c4 + 1], xr[4 * c4 + 2], xr[4 * c4 + 3]);
  }
  float* prow = Pt + (size_t)gid * 64;
  float* qrow = Qt + (size_t)gid * 64;
  for (int o = 0; o < 64; ++o) {
    const float4* w1 = (const float4*)&wl[o * 128];
    const float4* w2 = (const float4*)&wl[o * 128 + 64];
    float pa = 0.f, pb = 0.f, qa = 0.f, qb = 0.f;
#pragma unroll
    for (int c4 = 0; c4 < 16; c4 += 2) {
      float4 wa = w1[c4], wb = w1[c4 + 1];
      float4 va = w2[c4], vb = w2[c4 + 1];
      pa = fmaf(xr[4 * c4 + 0], wa.x, pa);
      pa = fmaf(xr[4 * c4 + 1], wa.y, pa);
      pa = fmaf(xr[4 * c4 + 2], wa.z, pa);
      pa = fmaf(xr[4 * c4 + 3], wa.w, pa);
      pb = fmaf(xr[4 * c4 + 4], wb.x, pb);
      pb = fmaf(xr[4 * c4 + 5], wb.y, pb);
      pb = fmaf(xr[4 * c4 + 6], wb.z, pb);
      pb = fmaf(xr[4 * c4 + 7], wb.w, pb);
      qa = fmaf(xr[4 * c4 + 0], va.x, qa);
      qa = fmaf(xr[4 * c4 + 1], va.y, qa);
      qa = fmaf(xr[4 * c4 + 2], va.z, qa);
      qa = fmaf(xr[4 * c4 + 3], va.w, qa);
      qb = fmaf(xr[4 * c4 + 4], vb.x, qb);
      qb = fmaf(xr[4 * c4 + 5], vb.y, qb);
      qb = fmaf(xr[4 * c4 + 6], vb.z, qb);
      qb = fmaf(xr[4 * c4 + 7], vb.w, qb);
    }
    float p = pa + pb;
    prow[o] = p;
    qrow[o] = (qa + qb) - p;
  }
}

// ---- Kernel B: fused score + per-row top-20 over one column segment ----
// score s = 2*dot(x_n, x_m) - xx[m]  (the -xx[n] term is row-constant).
// Column vectors come from xT at block-uniform addresses -> scalar loads,
// no LDS at all. Top-20 state lives entirely in VGPRs (launch_bounds caps
// occupancy pressure so nothing spills).
__global__ __launch_bounds__(256, 3) void kb(const float* __restrict__ xT,
                                             const float* __restrict__ xx,
                                             float* __restrict__ candv,
                                             int* __restrict__ candi) {
  int seg = blockIdx.x;  // 0..CS-1
  int rb = blockIdx.y;   // 0..15
  int b = blockIdx.z;    // 0..7
  int t = threadIdx.x;
  int n = rb * 256 + t;
  const float* xrp = xT + ((size_t)b * N_ + n) * 64;
  float xr2[64];
#pragma unroll
  for (int c4 = 0; c4 < 16; ++c4) {
    float4 v = *(const float4*)&xrp[c4 * 4];
    xr2[4 * c4 + 0] = 2.f * v.x;
    xr2[4 * c4 + 1] = 2.f * v.y;
    xr2[4 * c4 + 2] = 2.f * v.z;
    xr2[4 * c4 + 3] = 2.f * v.w;
  }
  float tv[20];
  int ti[20];
#pragma unroll
  for (int j = 0; j < 20; ++j) { tv[j] = -INFINITY; ti[j] = 0; }
  // 4-slot per-lane pending FIFO (static indexing only)
  float pv0 = 0.f, pv1 = 0.f, pv2 = 0.f, pv3 = 0.f;
  int pm0 = 0, pm1 = 0, pm2 = 0, pm3 = 0;
  int pcnt = 0;
  auto drain = [&]() {
    while (__any(pcnt > 0)) {
      bool a = pcnt > 0;
      float s2 = pv0;
      int m2 = pm0;
      if (a) {
        pv0 = pv1; pm0 = pm1;
        pv1 = pv2; pm1 = pm2;
        pv2 = pv3; pm2 = pm3;
        pcnt--;
        if (s2 > tv[19]) INS20(s2, m2);
      }
    }
  };
  const float* xcb = xT + (size_t)b * N_ * 64;
  const float* xxb = xx + (size_t)b * N_;
  const int m0 = seg * (N_ / CS);
  for (int m = m0; m < m0 + N_ / CS; ++m) {
    const float4* cp = (const float4*)(xcb + (size_t)m * 64);  // uniform addr
    float a0 = -xxb[m], a1 = 0.f, a2 = 0.f, a3 = 0.f;
#pragma unroll
    for (int c4 = 0; c4 < 16; ++c4) {
      float4 v = cp[c4];
      a0 = fmaf(xr2[4 * c4 + 0], v.x, a0);
      a1 = fmaf(xr2[4 * c4 + 1], v.y, a1);
      a2 = fmaf(xr2[4 * c4 + 2], v.z, a2);
      a3 = fmaf(xr2[4 * c4 + 3], v.w, a3);
    }
    float s = (a0 + a1) + (a2 + a3);
    bool q = s > tv[19];
    if (__any(q)) {
      if (q) {
        pv3 = (pcnt == 3) ? s : pv3; pm3 = (pcnt == 3) ? m : pm3;
        pv2 = (pcnt == 2) ? s : pv2; pm2 = (pcnt == 2) ? m : pm2;
        pv1 = (pcnt == 1) ? s : pv1; pm1 = (pcnt == 1) ? m : pm1;
        pv0 = (pcnt == 0) ? s : pv0; pm0 = (pcnt == 0) ? m : pm0;
        pcnt++;
      }
      if (__any(pcnt == 4)) drain();
    }
  }
  drain();
  size_t base = ((size_t)(b * N_ + n) * CS + seg) * 20;
#pragma unroll
  for (int j = 0; j < 20; ++j) {
    candv[base + j] = tv[j];
    candi[base + j] = ti[j];
  }
}

// ---------------- Merge partial top-20 lists ----------------
__global__ __launch_bounds__(256) void kmerge(const float* __restrict__ candv,
                                              const int* __restrict__ candi,
                                              int* __restrict__ idxf) {
  int r = blockIdx.x * 256 + threadIdx.x;  // 0..32767
  const float* cv = candv + (size_t)r * (CS * 20);
  const int* ci = candi + (size_t)r * (CS * 20);
  float tv[20];
  int ti[20];
#pragma unroll
  for (int j = 0; j < 20; ++j) { tv[j] = -INFINITY; ti[j] = 0; }
  for (int seg = 0; seg < CS; ++seg) {
    const float* cvs = cv + seg * 20;
    const int* cis = ci + seg * 20;
    for (int j = 0; j < 20; ++j) {
      float s = cvs[j];
      if (!(s > tv[19])) break;  // seg list sorted desc: rest can't qualify
      int m = cis[j];
      INS20(s, m);
    }
  }
  int* op = idxf + (size_t)r * 20;
#pragma unroll
  for (int j = 0; j < 20; ++j) op[j] = ti[j];
}

// ---- Kernel D: gather P at neighbors, stats, M = max_k P + Q ----
__global__ __launch_bounds__(256) void kd(const float* __restrict__ Pt,
                                          const float* __restrict__ Qt,
                                          const int* __restrict__ idxf,
                                          float* __restrict__ Mt,
                                          float* __restrict__ S1,
                                          float* __restrict__ S2) {
  int bi = blockIdx.x;  // 0..2047
  int b = bi >> 8;
  int n0 = (bi & 255) * 16;
  int w = threadIdx.x >> 6;
  int o = threadIdx.x & 63;
  const float* Pb = Pt + (size_t)b * N_ * 64;
  float s1 = 0.f, s2 = 0.f;
#pragma unroll
  for (int r = 0; r < 4; ++r) {
    int n = n0 + w * 4 + r;
    const int* ip = idxf + (size_t)(b * N_ + n) * 20;
    float a = 0.f, bb = 0.f, mx = -INFINITY;
#pragma unroll
    for (int k = 0; k < 20; ++k) {
      int m = ip[k];
      float v = Pb[(size_t)m * 64 + o];
      a += v;
      bb = fmaf(v, v, bb);
      mx = fmaxf(mx, v);
    }
    float q = Qt[(size_t)(b * N_ + n) * 64 + o];
    Mt[(size_t)(b * N_ + n) * 64 + o] = mx + q;
    s1 += a + 20.f * q;
    s2 += bb + 2.f * q * a + 20.f * q * q;
  }
  __shared__ float red[8][64];
  red[w][o] = s1;
  red[4 + w][o] = s2;
  __syncthreads();
  if (threadIdx.x < 64) {
    float t1 = red[0][o] + red[1][o] + red[2][o] + red[3][o];
    float t2 = red[4][o] + red[5][o] + red[6][o] + red[7][o];
    atomicAdd(&S1[b * 64 + o], t1);
    atomicAdd(&S2[b * 64 + o], t2);
  }
}

// ---- Kernel E: normalize + leaky + transpose to (B,O,N) ----
__global__ __launch_bounds__(256) void ke(const float* __restrict__ Mt,
                                          const float* __restrict__ S1,
                                          const float* __restrict__ S2,
                                          float* __restrict__ out) {
  __shared__ float tile[64 * 65];
  __shared__ float mu[64], rs[64];
  int bi = blockIdx.x;  // 0..511
  int b = bi >> 6;
  int n0 = (bi & 63) * 64;
  int t = threadIdx.x;
  if (t < 64) {
    float m = S1[b * 64 + t] * (1.f / NKf);
    float v = S2[b * 64 + t] * (1.f / NKf) - m * m;
    mu[t] = m;
    rs[t] = rsqrtf(v + EPS);
  }
#pragma unroll
  for (int rr = 0; rr < 16; ++rr) {
    int f = t + rr * 256;
    int nl = f >> 6, o = f & 63;
    tile[nl * 65 + o] = Mt[((size_t)b * N_ + n0 + nl) * 64 + o];
  }
  __syncthreads();
#pragma unroll
  for (int rr = 0; rr < 16; ++rr) {
    int f = t + rr * 256;
    int o = f >> 6, nl = f & 63;
    float v = (tile[nl * 65 + o] - mu[o]) * rs[o];
    v = v > 0.f ? v : SLOPE * v;
    out[((size_t)b * 64 + o) * N_ + n0 + nl] = v;
  }
}

extern "C" void kernel_launch(void* const* d_in, const int* in_sizes, int n_in,
                              void* d_out, int out_size, void* d_ws, size_t ws_size,
                              hipStream_t stream) {
  const float* x = (const float*)d_in[0];
  const float* W = (const float*)d_in[1];
  float* out = (float*)d_out;
  float* ws = (float*)d_ws;
  float* xx = ws;                            // 32768
  float* xT = xx + 32768;                    // 2097152  xT[b][n][c]
  float* Pt = xT + 2097152;                  // 2097152  P[b][n][o]
  float* Qt = Pt + 2097152;                  // 2097152  Q[b][n][o]
  float* candv = Qt + 2097152;               // 5242880
  int* candi = (int*)(candv + 5242880);      // 5242880
  int* idxf = candi + 5242880;               // 655360
  float* S1 = (float*)(idxf + 655360);       // 512
  float* S2 = S1 + 512;                      // 512
  float* Mt = xT;  // alias: xT dead after kb; Mt (2097152) fits exactly

  hipLaunchKernelGGL(ka, dim3(128), dim3(256), 0, stream, x, W, xx, xT, Pt, Qt);
  hipLaunchKernelGGL(kb, dim3(CS, 16, 8), dim3(256), 0, stream, xT, xx, candv, candi);
  hipLaunchKernelGGL(kmerge, dim3(128), dim3(256), 0, stream, candv, candi, idxf);
  hipMemsetAsync(S1, 0, 1024 * sizeof(float), stream);
  hipLaunchKernelGGL(kd, dim3(2048), dim3(256), 0, stream, Pt, Qt, idxf, Mt, S1, S2);
  hipLaunchKernelGGL(ke, dim3(512), dim3(256), 0, stream, Mt, S1, S2, out);
}